// Round 1
// baseline (530.365 us; speedup 1.0000x reference)
//
#include <hip/hip_runtime.h>

// Segment softmax grouped by dst. Round 4: payload counting-sort.
// Round-3 evidence: k_process = 212us, FETCH 399MB (2x random 32B gather of e
//   -> ~2x line overfetch), hbm 30% peak, VALU 2.7%, LDS-conflict ~1% =>
//   latency/granularity-bound on the e[id] gather. Fix: carry the 32B payload
//   through the sort. Scatter reads e COALESCED, computes exp once, writes
//   (exp[8], loc|id) into bin-sorted arrays (per-(block,bin) contiguous runs).
//   Process then streams the sorted payload coalesced; a statically-unrolled
//   8-edge register cache kills the second read for ~99% of edges.
// Predicted: proc FETCH 399->~117MB, dur 212->~50us; total ~180-220us.

#define HEADS 8
#define N_NODES 100000
#define BIN_SHIFT 7
#define BIN_WIDTH 128                      // 1 << BIN_SHIFT
#define NBINS 782                          // ceil(N_NODES / BIN_WIDTH)
#define TSTRIDE 9                          // pad 8 heads -> 9 floats: spread LDS banks
#define SB 512                             // histogram/scatter blocks
#define IDMASK 0x3FFFFFu                   // 22 bits: E = 3.2M < 2^22

__global__ void __launch_bounds__(1024)
k_hist(const int* __restrict__ dst, int E, int CH, unsigned* __restrict__ bincnt) {
    __shared__ unsigned h[NBINS];
    for (int j = threadIdx.x; j < NBINS; j += 1024) h[j] = 0u;
    __syncthreads();
    const int lo = blockIdx.x * CH, hi = min(E, lo + CH);
    for (int i = lo + threadIdx.x; i < hi; i += 1024)
        atomicAdd(&h[dst[i] >> BIN_SHIFT], 1u);
    __syncthreads();
    for (int j = threadIdx.x; j < NBINS; j += 1024) {
        unsigned c = h[j];
        if (c) atomicAdd(&bincnt[j], c);
    }
}

__global__ void __launch_bounds__(1024)
k_scan(const unsigned* __restrict__ bincnt, unsigned* __restrict__ binstart,
       unsigned* __restrict__ cursor, int E) {
    __shared__ unsigned s[1024];
    const int t = threadIdx.x;
    s[t] = (t < NBINS) ? bincnt[t] : 0u;
    __syncthreads();
    for (int off = 1; off < 1024; off <<= 1) {
        unsigned v = (t >= off) ? s[t - off] : 0u;
        __syncthreads();
        s[t] += v;
        __syncthreads();
    }
    if (t < NBINS) {
        unsigned st = (t == 0) ? 0u : s[t - 1];
        binstart[t] = st;
        cursor[t] = st;
    }
    if (t == 0) binstart[NBINS] = (unsigned)E;
}

// ---------- payload scatter: coalesced e read, exp once, sorted write ----------
__global__ void __launch_bounds__(1024)
k_scatter_pay(const float* __restrict__ e, const int* __restrict__ dst, int E, int CH,
              unsigned* __restrict__ cursor, float* __restrict__ se,
              unsigned* __restrict__ sid) {
    __shared__ unsigned h[NBINS];          // local count, then local cursor
    for (int j = threadIdx.x; j < NBINS; j += 1024) h[j] = 0u;
    __syncthreads();
    const int lo = blockIdx.x * CH, hi = min(E, lo + CH);
    for (int i = lo + threadIdx.x; i < hi; i += 1024)
        atomicAdd(&h[dst[i] >> BIN_SHIFT], 1u);
    __syncthreads();
    for (int j = threadIdx.x; j < NBINS; j += 1024) {
        unsigned c = h[j];
        h[j] = c ? atomicAdd(&cursor[j], c) : 0u;   // reserve contiguous run
    }
    __syncthreads();
    for (int i = lo + threadIdx.x; i < hi; i += 1024) {
        const int d = dst[i];
        const int bin = d >> BIN_SHIFT;
        const unsigned slot = atomicAdd(&h[bin], 1u);
        const float4* ep = reinterpret_cast<const float4*>(e) + (size_t)i * 2;
        float4 a = ep[0], b = ep[1];
        a.x = __expf(a.x); a.y = __expf(a.y); a.z = __expf(a.z); a.w = __expf(a.w);
        b.x = __expf(b.x); b.y = __expf(b.y); b.z = __expf(b.z); b.w = __expf(b.w);
        float4* sp = reinterpret_cast<float4*>(se) + (size_t)slot * 2;
        sp[0] = a;
        sp[1] = b;
        sid[slot] = ((unsigned)(d & (BIN_WIDTH - 1)) << 22) | (unsigned)i;
    }
}

// ---------- process: coalesced stream + 8-edge register cache ----------
__global__ void __launch_bounds__(512)
k_proc_pay(const float* __restrict__ se, const unsigned* __restrict__ sid,
           const unsigned* __restrict__ binstart, float* __restrict__ out) {
    __shared__ float tbl[BIN_WIDTH * TSTRIDE];
    for (int j = threadIdx.x; j < BIN_WIDTH * TSTRIDE; j += 512) tbl[j] = 0.0f;
    __syncthreads();
    const unsigned lo = binstart[blockIdx.x], hi = binstart[blockIdx.x + 1];

    float4 ca[8], cb[8];                   // 64 VGPR cache, statically indexed
    unsigned cu[8];
#pragma unroll
    for (int k = 0; k < 8; ++k) {
        const unsigned i = lo + threadIdx.x + (unsigned)k * 512u;
        if (i < hi) {
            const float4* sp = reinterpret_cast<const float4*>(se) + (size_t)i * 2;
            float4 a = sp[0], b = sp[1];
            const unsigned u = sid[i];
            ca[k] = a; cb[k] = b; cu[k] = u;
            float* t = tbl + (u >> 22) * TSTRIDE;
            atomicAdd(t + 0, a.x); atomicAdd(t + 1, a.y);
            atomicAdd(t + 2, a.z); atomicAdd(t + 3, a.w);
            atomicAdd(t + 4, b.x); atomicAdd(t + 5, b.y);
            atomicAdd(t + 6, b.z); atomicAdd(t + 7, b.w);
        }
    }
    // tail beyond register capacity (rare: bins ~Poisson(4092) vs 4096 cap)
    for (unsigned i = lo + threadIdx.x + 8u * 512u; i < hi; i += 512u) {
        const float4* sp = reinterpret_cast<const float4*>(se) + (size_t)i * 2;
        float4 a = sp[0], b = sp[1];
        float* t = tbl + (sid[i] >> 22) * TSTRIDE;
        atomicAdd(t + 0, a.x); atomicAdd(t + 1, a.y);
        atomicAdd(t + 2, a.z); atomicAdd(t + 3, a.w);
        atomicAdd(t + 4, b.x); atomicAdd(t + 5, b.y);
        atomicAdd(t + 6, b.z); atomicAdd(t + 7, b.w);
    }
    __syncthreads();
    for (int j = threadIdx.x; j < BIN_WIDTH * HEADS; j += 512) {
        const int idx = (j >> 3) * TSTRIDE + (j & 7);
        tbl[idx] = 1.0f / (tbl[idx] + 1e-16f);
    }
    __syncthreads();
#pragma unroll
    for (int k = 0; k < 8; ++k) {
        const unsigned i = lo + threadIdx.x + (unsigned)k * 512u;
        if (i < hi) {
            const unsigned u = cu[k];
            const float* t = tbl + (u >> 22) * TSTRIDE;
            float4 a = ca[k], b = cb[k];
            float4 o0, o1;
            o0.x = a.x * t[0]; o0.y = a.y * t[1]; o0.z = a.z * t[2]; o0.w = a.w * t[3];
            o1.x = b.x * t[4]; o1.y = b.y * t[5]; o1.z = b.z * t[6]; o1.w = b.w * t[7];
            float4* op = reinterpret_cast<float4*>(out) + (size_t)(u & IDMASK) * 2;
            op[0] = o0;
            op[1] = o1;
        }
    }
    for (unsigned i = lo + threadIdx.x + 8u * 512u; i < hi; i += 512u) {
        const float4* sp = reinterpret_cast<const float4*>(se) + (size_t)i * 2;
        float4 a = sp[0], b = sp[1];
        const unsigned u = sid[i];
        const float* t = tbl + (u >> 22) * TSTRIDE;
        float4 o0, o1;
        o0.x = a.x * t[0]; o0.y = a.y * t[1]; o0.z = a.z * t[2]; o0.w = a.w * t[3];
        o1.x = b.x * t[4]; o1.y = b.y * t[5]; o1.z = b.z * t[6]; o1.w = b.w * t[7];
        float4* op = reinterpret_cast<float4*>(out) + (size_t)(u & IDMASK) * 2;
        op[0] = o0;
        op[1] = o1;
    }
}

// ---------- mid fallback (ws fits ids only): round-3 pipeline ----------
__global__ void __launch_bounds__(1024)
k_scatter(const int* __restrict__ dst, int E, int CH,
          unsigned* __restrict__ cursor, unsigned* __restrict__ sorted) {
    __shared__ unsigned h[NBINS];
    for (int j = threadIdx.x; j < NBINS; j += 1024) h[j] = 0u;
    __syncthreads();
    const int lo = blockIdx.x * CH, hi = min(E, lo + CH);
    for (int i = lo + threadIdx.x; i < hi; i += 1024)
        atomicAdd(&h[dst[i] >> BIN_SHIFT], 1u);
    __syncthreads();
    for (int j = threadIdx.x; j < NBINS; j += 1024) {
        unsigned c = h[j];
        h[j] = c ? atomicAdd(&cursor[j], c) : 0u;
    }
    __syncthreads();
    for (int i = lo + threadIdx.x; i < hi; i += 1024) {
        const int d = dst[i];
        const int bin = d >> BIN_SHIFT;
        const unsigned slot = atomicAdd(&h[bin], 1u);
        sorted[slot] = ((unsigned)(d & (BIN_WIDTH - 1)) << 22) | (unsigned)i;
    }
}

__global__ void __launch_bounds__(512)
k_process(const float* __restrict__ e, const unsigned* __restrict__ sorted,
          const unsigned* __restrict__ binstart, float* __restrict__ out) {
    __shared__ float tbl[BIN_WIDTH * TSTRIDE];
    for (int j = threadIdx.x; j < BIN_WIDTH * TSTRIDE; j += 512) tbl[j] = 0.0f;
    __syncthreads();
    const unsigned lo = binstart[blockIdx.x], hi = binstart[blockIdx.x + 1];
    for (unsigned i = lo + threadIdx.x; i < hi; i += 512) {
        const unsigned u = sorted[i];
        const unsigned id = u & IDMASK;
        const unsigned loc = u >> 22;
        const float4* ep = reinterpret_cast<const float4*>(e) + (size_t)id * 2;
        float4 a = ep[0], b = ep[1];
        float* t = tbl + loc * TSTRIDE;
        atomicAdd(t + 0, __expf(a.x)); atomicAdd(t + 1, __expf(a.y));
        atomicAdd(t + 2, __expf(a.z)); atomicAdd(t + 3, __expf(a.w));
        atomicAdd(t + 4, __expf(b.x)); atomicAdd(t + 5, __expf(b.y));
        atomicAdd(t + 6, __expf(b.z)); atomicAdd(t + 7, __expf(b.w));
    }
    __syncthreads();
    for (int j = threadIdx.x; j < BIN_WIDTH * HEADS; j += 512) {
        const int idx = (j >> 3) * TSTRIDE + (j & 7);
        tbl[idx] = 1.0f / (tbl[idx] + 1e-16f);
    }
    __syncthreads();
    for (unsigned i = lo + threadIdx.x; i < hi; i += 512) {
        const unsigned u = sorted[i];
        const unsigned id = u & IDMASK;
        const unsigned loc = u >> 22;
        const float4* ep = reinterpret_cast<const float4*>(e) + (size_t)id * 2;
        float4 a = ep[0], b = ep[1];
        const float* t = tbl + loc * TSTRIDE;
        float4 o0, o1;
        o0.x = __expf(a.x) * t[0]; o0.y = __expf(a.y) * t[1];
        o0.z = __expf(a.z) * t[2]; o0.w = __expf(a.w) * t[3];
        o1.x = __expf(b.x) * t[4]; o1.y = __expf(b.y) * t[5];
        o1.z = __expf(b.z) * t[6]; o1.w = __expf(b.w) * t[7];
        float4* op = reinterpret_cast<float4*>(out) + (size_t)id * 2;
        op[0] = o0;
        op[1] = o1;
    }
}

// ---------- last-resort fallback: global-atomic path ----------
__global__ void __launch_bounds__(256)
fb_seg_sum(const float* __restrict__ e, const int* __restrict__ dst,
           float* __restrict__ seg, int E) {
    int i = blockIdx.x * blockDim.x + threadIdx.x;
    if (i >= E) return;
    int d = dst[i];
    const float4* ep = reinterpret_cast<const float4*>(e) + (size_t)i * 2;
    float4 a = ep[0], b = ep[1];
    float* base = seg + (size_t)d * HEADS;
    atomicAdd(base + 0, __expf(a.x)); atomicAdd(base + 1, __expf(a.y));
    atomicAdd(base + 2, __expf(a.z)); atomicAdd(base + 3, __expf(a.w));
    atomicAdd(base + 4, __expf(b.x)); atomicAdd(base + 5, __expf(b.y));
    atomicAdd(base + 6, __expf(b.z)); atomicAdd(base + 7, __expf(b.w));
}
__global__ void __launch_bounds__(256)
fb_norm(const float* __restrict__ e, const int* __restrict__ dst,
        const float* __restrict__ seg, float* __restrict__ out, int E) {
    int i = blockIdx.x * blockDim.x + threadIdx.x;
    if (i >= E) return;
    int d = dst[i];
    const float4* ep = reinterpret_cast<const float4*>(e) + (size_t)i * 2;
    float4 a = ep[0], b = ep[1];
    const float4* sp = reinterpret_cast<const float4*>(seg) + (size_t)d * 2;
    float4 s0 = sp[0], s1 = sp[1];
    float4 o0, o1;
    o0.x = __expf(a.x) / (s0.x + 1e-16f); o0.y = __expf(a.y) / (s0.y + 1e-16f);
    o0.z = __expf(a.z) / (s0.z + 1e-16f); o0.w = __expf(a.w) / (s0.w + 1e-16f);
    o1.x = __expf(b.x) / (s1.x + 1e-16f); o1.y = __expf(b.y) / (s1.y + 1e-16f);
    o1.z = __expf(b.z) / (s1.z + 1e-16f); o1.w = __expf(b.w) / (s1.w + 1e-16f);
    float4* op = reinterpret_cast<float4*>(out) + (size_t)i * 2;
    op[0] = o0; op[1] = o1;
}

extern "C" void kernel_launch(void* const* d_in, const int* in_sizes, int n_in,
                              void* d_out, int out_size, void* d_ws, size_t ws_size,
                              hipStream_t stream) {
    const float* e = (const float*)d_in[0];
    const int* edge_index = (const int*)d_in[1];
    const int E = in_sizes[0] / HEADS;
    const int* dst = edge_index + E;           // row 1 of [2, E]
    float* out = (float*)d_out;

    const size_t meta = (size_t)(3 * NBINS + 2) * 4;
    const size_t needPay = (size_t)E * (HEADS * 4 + 4) + meta;   // se + sid + meta
    const size_t needIdx = (size_t)E * 4 + meta;

    if (E <= (1 << 22) && ws_size >= needPay) {
        // ---- payload-sort path ----
        float* se = (float*)d_ws;                       // E*8 floats
        unsigned* sid = (unsigned*)(se + (size_t)E * HEADS);  // E words
        unsigned* bincnt = sid + E;                     // NBINS
        unsigned* binstart = bincnt + NBINS;            // NBINS+1
        unsigned* cursor = binstart + NBINS + 1;        // NBINS

        hipMemsetAsync(bincnt, 0, NBINS * sizeof(unsigned), stream);
        const int CH = (E + SB - 1) / SB;
        k_hist       <<<SB, 1024, 0, stream>>>(dst, E, CH, bincnt);
        k_scan       <<<1, 1024, 0, stream>>>(bincnt, binstart, cursor, E);
        k_scatter_pay<<<SB, 1024, 0, stream>>>(e, dst, E, CH, cursor, se, sid);
        k_proc_pay   <<<NBINS, 512, 0, stream>>>(se, sid, binstart, out);
        return;
    }

    if (E <= (1 << 22) && ws_size >= needIdx) {
        // ---- id-sort path (round 3) ----
        unsigned* sorted   = (unsigned*)d_ws;
        unsigned* bincnt   = sorted + E;
        unsigned* binstart = bincnt + NBINS;
        unsigned* cursor   = binstart + NBINS + 1;

        hipMemsetAsync(bincnt, 0, NBINS * sizeof(unsigned), stream);
        const int CH = (E + SB - 1) / SB;
        k_hist   <<<SB, 1024, 0, stream>>>(dst, E, CH, bincnt);
        k_scan   <<<1, 1024, 0, stream>>>(bincnt, binstart, cursor, E);
        k_scatter<<<SB, 1024, 0, stream>>>(dst, E, CH, cursor, sorted);
        k_process<<<NBINS, 512, 0, stream>>>(e, sorted, binstart, out);
        return;
    }

    // ---- atomic fallback ----
    float* seg = (float*)d_ws;
    hipMemsetAsync(seg, 0, (size_t)N_NODES * HEADS * sizeof(float), stream);
    const int grid = (E + 255) / 256;
    fb_seg_sum<<<grid, 256, 0, stream>>>(e, dst, seg, E);
    fb_norm<<<grid, 256, 0, stream>>>(e, dst, seg, out, E);
}

// Round 2
// 436.464 us; speedup vs baseline: 1.2151x; 1.2151x over previous
//
#include <hip/hip_runtime.h>

// Segment softmax grouped by dst. Round 5: kill the fp32 CAS-loop atomics.
// Round-4 evidence: k_proc_pay 212us with FETCH 57MB, HBM 9.8%, VALU 0.9%,
//   LDS-conflict ~1%, occupancy 32% -- EVERY pipe idle, yet identical duration
//   to round-3's k_process (FETCH 399MB, HBM 30%). Only invariant: 25.6M
//   atomicAdd(float*) to LDS at a measured 0.2 lane-ops/cy/CU (~25x below
//   native ds_add_f32). Diagnosis: HIP atomicAdd(float*) lowers to a CAS loop
//   (IEEE-safe); contended retries serialize in lgkmcnt waits, invisible to
//   the bank-conflict counter. Fix: unsafeAtomicAdd -> native ds_add_f32.
// Also revert round-4's payload sort (+128us of scattered 36B writes, zero
//   gain since proc was atomic-bound, not gather-bound). Id-sort + reg cache;
//   pass-2 reuses pass-1 exp values, tail re-gathers from L3-resident e.
// Predicted: proc 212 -> 55-80us (FETCH ~200-260MB, HBM 40-60%); total ~260-300us.

#define HEADS 8
#define N_NODES 100000
#define BIN_SHIFT 7
#define BIN_WIDTH 128                      // 1 << BIN_SHIFT
#define NBINS 782                          // ceil(N_NODES / BIN_WIDTH)
#define TSTRIDE 9                          // pad 8 heads -> 9 floats: spread LDS banks
#define SB 512                             // histogram/scatter blocks
#define IDMASK 0x3FFFFFu                   // 22 bits: E = 3.2M < 2^22

// HIP atomicAdd(float*) emits an IEEE-safe CAS loop; unsafeAtomicAdd emits the
// native ds_add_f32 / global_atomic_add_f32. Values are post-exp (>0, no
// denorm correctness concern) and tolerance is ~1e-3.
__device__ __forceinline__ void ldsAdd(float* p, float v) {
    unsafeAtomicAdd(p, v);
}

__global__ void __launch_bounds__(1024)
k_hist(const int* __restrict__ dst, int E, int CH, unsigned* __restrict__ bincnt) {
    __shared__ unsigned h[NBINS];
    for (int j = threadIdx.x; j < NBINS; j += 1024) h[j] = 0u;
    __syncthreads();
    const int lo = blockIdx.x * CH, hi = min(E, lo + CH);
    for (int i = lo + threadIdx.x; i < hi; i += 1024)
        atomicAdd(&h[dst[i] >> BIN_SHIFT], 1u);
    __syncthreads();
    for (int j = threadIdx.x; j < NBINS; j += 1024) {
        unsigned c = h[j];
        if (c) atomicAdd(&bincnt[j], c);
    }
}

__global__ void __launch_bounds__(1024)
k_scan(const unsigned* __restrict__ bincnt, unsigned* __restrict__ binstart,
       unsigned* __restrict__ cursor, int E) {
    __shared__ unsigned s[1024];
    const int t = threadIdx.x;
    s[t] = (t < NBINS) ? bincnt[t] : 0u;
    __syncthreads();
    for (int off = 1; off < 1024; off <<= 1) {
        unsigned v = (t >= off) ? s[t - off] : 0u;
        __syncthreads();
        s[t] += v;
        __syncthreads();
    }
    if (t < NBINS) {
        unsigned st = (t == 0) ? 0u : s[t - 1];
        binstart[t] = st;
        cursor[t] = st;
    }
    if (t == 0) binstart[NBINS] = (unsigned)E;
}

__global__ void __launch_bounds__(1024)
k_scatter(const int* __restrict__ dst, int E, int CH,
          unsigned* __restrict__ cursor, unsigned* __restrict__ sorted) {
    __shared__ unsigned h[NBINS];          // local count, then local cursor
    for (int j = threadIdx.x; j < NBINS; j += 1024) h[j] = 0u;
    __syncthreads();
    const int lo = blockIdx.x * CH, hi = min(E, lo + CH);
    for (int i = lo + threadIdx.x; i < hi; i += 1024)
        atomicAdd(&h[dst[i] >> BIN_SHIFT], 1u);
    __syncthreads();
    for (int j = threadIdx.x; j < NBINS; j += 1024) {
        unsigned c = h[j];
        h[j] = c ? atomicAdd(&cursor[j], c) : 0u;   // reserve contiguous run
    }
    __syncthreads();
    for (int i = lo + threadIdx.x; i < hi; i += 1024) {
        const int d = dst[i];
        const int bin = d >> BIN_SHIFT;
        const unsigned slot = atomicAdd(&h[bin], 1u);
        sorted[slot] = ((unsigned)(d & (BIN_WIDTH - 1)) << 22) | (unsigned)i;
    }
}

// ---------- process: gather once, native LDS atomics, reg-cached pass 2 ----------
__global__ void __launch_bounds__(512)
k_process(const float* __restrict__ e, const unsigned* __restrict__ sorted,
          const unsigned* __restrict__ binstart, float* __restrict__ out) {
    __shared__ float tbl[BIN_WIDTH * TSTRIDE];
    for (int j = threadIdx.x; j < BIN_WIDTH * TSTRIDE; j += 512) tbl[j] = 0.0f;
    __syncthreads();
    const unsigned lo = binstart[blockIdx.x], hi = binstart[blockIdx.x + 1];

    float4 ca[8], cb[8];                   // statically-indexed reg cache
    unsigned cu[8];
#pragma unroll
    for (int k = 0; k < 8; ++k) {
        const unsigned i = lo + threadIdx.x + (unsigned)k * 512u;
        float4 a = make_float4(0.f, 0.f, 0.f, 0.f);
        float4 b = make_float4(0.f, 0.f, 0.f, 0.f);
        unsigned u = 0u;
        if (i < hi) {
            u = sorted[i];
            const float4* ep = reinterpret_cast<const float4*>(e)
                             + (size_t)(u & IDMASK) * 2;
            a = ep[0]; b = ep[1];
            a.x = __expf(a.x); a.y = __expf(a.y);
            a.z = __expf(a.z); a.w = __expf(a.w);
            b.x = __expf(b.x); b.y = __expf(b.y);
            b.z = __expf(b.z); b.w = __expf(b.w);
            float* t = tbl + (u >> 22) * TSTRIDE;
            ldsAdd(t + 0, a.x); ldsAdd(t + 1, a.y);
            ldsAdd(t + 2, a.z); ldsAdd(t + 3, a.w);
            ldsAdd(t + 4, b.x); ldsAdd(t + 5, b.y);
            ldsAdd(t + 6, b.z); ldsAdd(t + 7, b.w);
        }
        ca[k] = a; cb[k] = b; cu[k] = u;
    }
    // tail beyond register capacity (bins ~Poisson(4092) vs 4096 cap: rare)
    for (unsigned i = lo + threadIdx.x + 4096u; i < hi; i += 512u) {
        const unsigned u = sorted[i];
        const float4* ep = reinterpret_cast<const float4*>(e)
                         + (size_t)(u & IDMASK) * 2;
        float4 a = ep[0], b = ep[1];
        float* t = tbl + (u >> 22) * TSTRIDE;
        ldsAdd(t + 0, __expf(a.x)); ldsAdd(t + 1, __expf(a.y));
        ldsAdd(t + 2, __expf(a.z)); ldsAdd(t + 3, __expf(a.w));
        ldsAdd(t + 4, __expf(b.x)); ldsAdd(t + 5, __expf(b.y));
        ldsAdd(t + 6, __expf(b.z)); ldsAdd(t + 7, __expf(b.w));
    }
    __syncthreads();
    for (int j = threadIdx.x; j < BIN_WIDTH * HEADS; j += 512) {
        const int idx = (j >> 3) * TSTRIDE + (j & 7);
        tbl[idx] = 1.0f / (tbl[idx] + 1e-16f);
    }
    __syncthreads();
#pragma unroll
    for (int k = 0; k < 8; ++k) {
        const unsigned i = lo + threadIdx.x + (unsigned)k * 512u;
        if (i < hi) {
            const unsigned u = cu[k];
            const float* t = tbl + (u >> 22) * TSTRIDE;
            float4 a = ca[k], b = cb[k];
            float4 o0, o1;
            o0.x = a.x * t[0]; o0.y = a.y * t[1];
            o0.z = a.z * t[2]; o0.w = a.w * t[3];
            o1.x = b.x * t[4]; o1.y = b.y * t[5];
            o1.z = b.z * t[6]; o1.w = b.w * t[7];
            float4* op = reinterpret_cast<float4*>(out) + (size_t)(u & IDMASK) * 2;
            op[0] = o0;
            op[1] = o1;
        }
    }
    for (unsigned i = lo + threadIdx.x + 4096u; i < hi; i += 512u) {
        const unsigned u = sorted[i];
        const float4* ep = reinterpret_cast<const float4*>(e)
                         + (size_t)(u & IDMASK) * 2;
        float4 a = ep[0], b = ep[1];
        const float* t = tbl + (u >> 22) * TSTRIDE;
        float4 o0, o1;
        o0.x = __expf(a.x) * t[0]; o0.y = __expf(a.y) * t[1];
        o0.z = __expf(a.z) * t[2]; o0.w = __expf(a.w) * t[3];
        o1.x = __expf(b.x) * t[4]; o1.y = __expf(b.y) * t[5];
        o1.z = __expf(b.z) * t[6]; o1.w = __expf(b.w) * t[7];
        float4* op = reinterpret_cast<float4*>(out) + (size_t)(u & IDMASK) * 2;
        op[0] = o0;
        op[1] = o1;
    }
}

// ---------- last-resort fallback: global-atomic path ----------
__global__ void __launch_bounds__(256)
fb_seg_sum(const float* __restrict__ e, const int* __restrict__ dst,
           float* __restrict__ seg, int E) {
    int i = blockIdx.x * blockDim.x + threadIdx.x;
    if (i >= E) return;
    int d = dst[i];
    const float4* ep = reinterpret_cast<const float4*>(e) + (size_t)i * 2;
    float4 a = ep[0], b = ep[1];
    float* base = seg + (size_t)d * HEADS;
    unsafeAtomicAdd(base + 0, __expf(a.x)); unsafeAtomicAdd(base + 1, __expf(a.y));
    unsafeAtomicAdd(base + 2, __expf(a.z)); unsafeAtomicAdd(base + 3, __expf(a.w));
    unsafeAtomicAdd(base + 4, __expf(b.x)); unsafeAtomicAdd(base + 5, __expf(b.y));
    unsafeAtomicAdd(base + 6, __expf(b.z)); unsafeAtomicAdd(base + 7, __expf(b.w));
}
__global__ void __launch_bounds__(256)
fb_norm(const float* __restrict__ e, const int* __restrict__ dst,
        const float* __restrict__ seg, float* __restrict__ out, int E) {
    int i = blockIdx.x * blockDim.x + threadIdx.x;
    if (i >= E) return;
    int d = dst[i];
    const float4* ep = reinterpret_cast<const float4*>(e) + (size_t)i * 2;
    float4 a = ep[0], b = ep[1];
    const float4* sp = reinterpret_cast<const float4*>(seg) + (size_t)d * 2;
    float4 s0 = sp[0], s1 = sp[1];
    float4 o0, o1;
    o0.x = __expf(a.x) / (s0.x + 1e-16f); o0.y = __expf(a.y) / (s0.y + 1e-16f);
    o0.z = __expf(a.z) / (s0.z + 1e-16f); o0.w = __expf(a.w) / (s0.w + 1e-16f);
    o1.x = __expf(b.x) / (s1.x + 1e-16f); o1.y = __expf(b.y) / (s1.y + 1e-16f);
    o1.z = __expf(b.z) / (s1.z + 1e-16f); o1.w = __expf(b.w) / (s1.w + 1e-16f);
    float4* op = reinterpret_cast<float4*>(out) + (size_t)i * 2;
    op[0] = o0; op[1] = o1;
}

extern "C" void kernel_launch(void* const* d_in, const int* in_sizes, int n_in,
                              void* d_out, int out_size, void* d_ws, size_t ws_size,
                              hipStream_t stream) {
    const float* e = (const float*)d_in[0];
    const int* edge_index = (const int*)d_in[1];
    const int E = in_sizes[0] / HEADS;
    const int* dst = edge_index + E;           // row 1 of [2, E]
    float* out = (float*)d_out;

    const size_t meta = (size_t)(3 * NBINS + 2) * 4;
    const size_t needIdx = (size_t)E * 4 + meta;

    if (E <= (1 << 22) && ws_size >= needIdx) {
        // ---- id-sort path ----
        unsigned* sorted   = (unsigned*)d_ws;          // E words
        unsigned* bincnt   = sorted + E;               // NBINS
        unsigned* binstart = bincnt + NBINS;           // NBINS+1
        unsigned* cursor   = binstart + NBINS + 1;     // NBINS

        hipMemsetAsync(bincnt, 0, NBINS * sizeof(unsigned), stream);
        const int CH = (E + SB - 1) / SB;
        k_hist   <<<SB, 1024, 0, stream>>>(dst, E, CH, bincnt);
        k_scan   <<<1, 1024, 0, stream>>>(bincnt, binstart, cursor, E);
        k_scatter<<<SB, 1024, 0, stream>>>(dst, E, CH, cursor, sorted);
        k_process<<<NBINS, 512, 0, stream>>>(e, sorted, binstart, out);
        return;
    }

    // ---- atomic fallback ----
    float* seg = (float*)d_ws;
    hipMemsetAsync(seg, 0, (size_t)N_NODES * HEADS * sizeof(float), stream);
    const int grid = (E + 255) / 256;
    fb_seg_sum<<<grid, 256, 0, stream>>>(e, dst, seg, E);
    fb_norm<<<grid, 256, 0, stream>>>(e, dst, seg, out, E);
}